// Round 1
// baseline (1443.394 us; speedup 1.0000x reference)
//
#include <hip/hip_runtime.h>
#include <math.h>

#define B_   16
#define N_   4096
#define C_   512
#define CF_  256
#define NH_  8
#define HD_  32
#define FHD_ 128
#define EPS_ 1e-4f
#define PI2F 1.5707963267948966f

__device__ __forceinline__ float abs_clamp(float t) {
    float a = fminf(fmaxf(fabsf(t), 1e-4f), 1e4f);
    return t > 0.f ? a : (t < 0.f ? -a : 0.f);
}

// ---------------------------------------------------------------- SE: mean over tokens
__global__ __launch_bounds__(256) void se_sum_kernel(const float* __restrict__ q,
                                                     float* __restrict__ sesum) {
    int b = blockIdx.x, chunk = blockIdx.y;
    int c = threadIdx.x;  // 0..255
    const float* p = q + ((size_t)b * N_ + (size_t)chunk * 256) * C_;
    float a0 = 0.f, a1 = 0.f;
    for (int n = 0; n < 256; n++) {
        a0 += p[(size_t)n * C_ + c];
        a1 += p[(size_t)n * C_ + c + 256];
    }
    atomicAdd(&sesum[b * C_ + c], a0);
    atomicAdd(&sesum[b * C_ + c + 256], a1);
}

// ---------------------------------------------------------------- SE: 2-layer MLP + sigmoid
__global__ __launch_bounds__(256) void se_gate_kernel(const float* __restrict__ sesum,
                                                      const float* __restrict__ Wse1,
                                                      const float* __restrict__ Wse2,
                                                      float* __restrict__ segate) {
    __shared__ float sm[C_];
    __shared__ float hm[C_ / 2];
    int b = blockIdx.x, t = threadIdx.x;
    sm[t]       = sesum[b * C_ + t]       * (1.f / N_);
    sm[t + 256] = sesum[b * C_ + t + 256] * (1.f / N_);
    __syncthreads();
    {   // h[j] = relu(sum_c mean[c] * Wse1[j,c]), j = t
        const float* w = Wse1 + (size_t)t * C_;
        float acc = 0.f;
        for (int c2 = 0; c2 < C_; c2++) acc += sm[c2] * w[c2];
        hm[t] = fmaxf(acc, 0.f);
    }
    __syncthreads();
    for (int r = 0; r < 2; r++) {
        int c2 = t + r * 256;
        const float* w2 = Wse2 + (size_t)c2 * (C_ / 2);
        float a2 = 0.f;
        for (int j = 0; j < C_ / 2; j++) a2 += hm[j] * w2[j];
        segate[b * C_ + c2] = 1.f / (1.f + expf(-a2));
    }
}

// ---------------------------------------------------------------- fused q/k/v projection GEMM
// C[m,n] = A[m,:] . W[n,:]  (A row-major MxK, W row-major NxK), K=512, +bias, relu for q/k
__global__ __launch_bounds__(256) void qkv_gemm(const float* __restrict__ A,
                                                const float* __restrict__ Wq, const float* __restrict__ bq,
                                                const float* __restrict__ Wk, const float* __restrict__ bk,
                                                const float* __restrict__ Wv, const float* __restrict__ bv,
                                                float* __restrict__ qo, float* __restrict__ ko,
                                                float* __restrict__ vo) {
    __shared__ float As[16][132];
    __shared__ float Bs[16][132];
    int t = threadIdx.x;
    int bm = blockIdx.x;       // 0..511  (M tile)
    int by = blockIdx.y;       // 0..5    (2 tiles per matrix)
    int mat = by >> 1;
    int nc0 = (by & 1) * 128;
    const float* W    = (mat == 0) ? Wq : (mat == 1) ? Wk : Wv;
    const float* bias = (mat == 0) ? bq : (mat == 1) ? bk : bv;
    float* O          = (mat == 0) ? qo : (mat == 1) ? ko : vo;
    bool dorelu = (mat < 2);

    int lr = t >> 1;           // 0..127
    int lc = (t & 1) * 8;      // 0 or 8
    const float* Ap = A + ((size_t)bm * 128 + lr) * C_ + lc;
    const float* Wp = W + ((size_t)(nc0 + lr)) * C_ + lc;

    float acc[2][2][4][4];
#pragma unroll
    for (int i = 0; i < 2; i++)
#pragma unroll
        for (int j = 0; j < 2; j++)
#pragma unroll
            for (int u = 0; u < 4; u++)
#pragma unroll
                for (int w = 0; w < 4; w++) acc[i][j][u][w] = 0.f;

    int tx = t & 15, ty = t >> 4;

    for (int k0 = 0; k0 < C_; k0 += 16) {
        float4 a0 = *(const float4*)(Ap + k0);
        float4 a1 = *(const float4*)(Ap + k0 + 4);
        float4 b0 = *(const float4*)(Wp + k0);
        float4 b1 = *(const float4*)(Wp + k0 + 4);
        __syncthreads();
        As[lc + 0][lr] = a0.x; As[lc + 1][lr] = a0.y; As[lc + 2][lr] = a0.z; As[lc + 3][lr] = a0.w;
        As[lc + 4][lr] = a1.x; As[lc + 5][lr] = a1.y; As[lc + 6][lr] = a1.z; As[lc + 7][lr] = a1.w;
        Bs[lc + 0][lr] = b0.x; Bs[lc + 1][lr] = b0.y; Bs[lc + 2][lr] = b0.z; Bs[lc + 3][lr] = b0.w;
        Bs[lc + 4][lr] = b1.x; Bs[lc + 5][lr] = b1.y; Bs[lc + 6][lr] = b1.z; Bs[lc + 7][lr] = b1.w;
        __syncthreads();
#pragma unroll
        for (int kk = 0; kk < 16; kk++) {
            float4 a0v = *(const float4*)&As[kk][ty * 4];
            float4 a1v = *(const float4*)&As[kk][ty * 4 + 64];
            float4 b0v = *(const float4*)&Bs[kk][tx * 4];
            float4 b1v = *(const float4*)&Bs[kk][tx * 4 + 64];
            float av[2][4] = {{a0v.x, a0v.y, a0v.z, a0v.w}, {a1v.x, a1v.y, a1v.z, a1v.w}};
            float bv2[2][4] = {{b0v.x, b0v.y, b0v.z, b0v.w}, {b1v.x, b1v.y, b1v.z, b1v.w}};
#pragma unroll
            for (int i = 0; i < 2; i++)
#pragma unroll
                for (int u = 0; u < 4; u++)
#pragma unroll
                    for (int j = 0; j < 2; j++)
#pragma unroll
                        for (int w = 0; w < 4; w++) acc[i][j][u][w] += av[i][u] * bv2[j][w];
        }
    }

#pragma unroll
    for (int i = 0; i < 2; i++)
#pragma unroll
        for (int u = 0; u < 4; u++) {
            size_t m = (size_t)bm * 128 + i * 64 + ty * 4 + u;
#pragma unroll
            for (int j = 0; j < 2; j++) {
                int ncl = nc0 + j * 64 + tx * 4;
                float4 bb = *(const float4*)(bias + ncl);
                float4 o;
                o.x = acc[i][j][u][0] + bb.x;
                o.y = acc[i][j][u][1] + bb.y;
                o.z = acc[i][j][u][2] + bb.z;
                o.w = acc[i][j][u][3] + bb.w;
                if (dorelu) {
                    o.x = fmaxf(o.x, 0.f); o.y = fmaxf(o.y, 0.f);
                    o.z = fmaxf(o.z, 0.f); o.w = fmaxf(o.w, 0.f);
                }
                *(float4*)(O + m * CF_ + ncl) = o;
            }
        }
}

// ---------------------------------------------------------------- kv state + k_sum
// kv[b,h,f,d] = sum_n trig_{f>>5}(n) * k[b,n,h,f&31] * v[b,n,h,d]   (clamp at consumption)
// ksum[b,h,f] = sum_n trig_{f>>5}(n) * k[b,n,h,f&31]
__global__ __launch_bounds__(256) void kv_kernel(const float* __restrict__ kin,
                                                 const float* __restrict__ vin,
                                                 float* __restrict__ kvout,
                                                 float* __restrict__ ksum) {
    int chunk = blockIdx.x;    // 0..7  (512 tokens each)
    int h = blockIdx.y, b = blockIdx.z;
    int t = threadIdx.x;
    __shared__ float kb[32][32];
    __shared__ float vb[32][32];
    __shared__ float tb[32][4];

    int i = t & 15, j = t >> 4;     // d' pair (2i,2i+1), d pair (2j,2j+1)
    float acc[4][2][2];
#pragma unroll
    for (int a = 0; a < 4; a++)
#pragma unroll
        for (int x = 0; x < 2; x++)
#pragma unroll
            for (int y = 0; y < 2; y++) acc[a][x][y] = 0.f;
    float ksacc = 0.f;

    for (int s = 0; s < 16; s++) {
        int n0 = chunk * 512 + s * 32;
        __syncthreads();
#pragma unroll
        for (int r = 0; r < 4; r++) {
            int idx = t + r * 256;
            int tok = idx >> 5, d = idx & 31;
            size_t g = ((size_t)b * N_ + n0 + tok) * CF_ + h * HD_ + d;
            kb[tok][d] = kin[g];
            vb[tok][d] = vin[g];
        }
        if (t < 32) {
            int n = n0 + t;
            float ra = (float)(n >> 6), cb = (float)(n & 63);
            float aa = (PI2F * ra) / 64.0f;
            float ab = (PI2F * cb) / 64.0f;
            tb[t][0] = cosf(aa); tb[t][1] = sinf(aa);
            tb[t][2] = cosf(ab); tb[t][3] = sinf(ab);
        }
        __syncthreads();
        for (int n = 0; n < 32; n++) {
            float t0 = tb[n][0], t1 = tb[n][1], t2 = tb[n][2], t3 = tb[n][3];
            float ka = kb[n][2 * i], ka2 = kb[n][2 * i + 1];
            float va = vb[n][2 * j], va2 = vb[n][2 * j + 1];
            float p;
            p = ka * t0;  acc[0][0][0] += p * va; acc[0][0][1] += p * va2;
            p = ka2 * t0; acc[0][1][0] += p * va; acc[0][1][1] += p * va2;
            p = ka * t1;  acc[1][0][0] += p * va; acc[1][0][1] += p * va2;
            p = ka2 * t1; acc[1][1][0] += p * va; acc[1][1][1] += p * va2;
            p = ka * t2;  acc[2][0][0] += p * va; acc[2][0][1] += p * va2;
            p = ka2 * t2; acc[2][1][0] += p * va; acc[2][1][1] += p * va2;
            p = ka * t3;  acc[3][0][0] += p * va; acc[3][0][1] += p * va2;
            p = ka2 * t3; acc[3][1][0] += p * va; acc[3][1][1] += p * va2;
        }
        if (t < 128) {  // ksum: f = t
            int ti = t >> 5, dd = t & 31;
            for (int n = 0; n < 32; n++) ksacc += tb[n][ti] * kb[n][dd];
        }
    }

    float* kvp = kvout + ((size_t)(b * NH_ + h)) * FHD_ * HD_;
#pragma unroll
    for (int a = 0; a < 4; a++)
#pragma unroll
        for (int x = 0; x < 2; x++)
#pragma unroll
            for (int y = 0; y < 2; y++)
                atomicAdd(&kvp[(size_t)(a * 32 + 2 * i + x) * HD_ + 2 * j + y], acc[a][x][y]);
    if (t < 128) atomicAdd(&ksum[(size_t)(b * NH_ + h) * FHD_ + t], ksacc);
}

// ---------------------------------------------------------------- attention lookup (in-place over q)
__global__ __launch_bounds__(256) void attn_kernel(float* __restrict__ qbuf,
                                                   const float* __restrict__ kvin,
                                                   const float* __restrict__ ksum) {
    int chunk = blockIdx.x;    // 0..31 (128 tokens)
    int h = blockIdx.y, b = blockIdx.z;
    int t = threadIdx.x;
    __shared__ float kvS[128][32];
    __shared__ float qS[128][33];
    __shared__ float tS[128][4];
    __shared__ float ksS[128];
    __shared__ float zS[128];
    int n0 = chunk * 128;

    const float* kvp = kvin + ((size_t)(b * NH_ + h)) * FHD_ * HD_;
#pragma unroll
    for (int r = 0; r < 16; r++) {
        int idx = t + r * 256;
        (&kvS[0][0])[idx] = abs_clamp(kvp[idx]);   // clamp(kv) here, after complete sum
    }
    if (t < 128) ksS[t] = ksum[(size_t)(b * NH_ + h) * FHD_ + t];
#pragma unroll
    for (int r = 0; r < 16; r++) {
        int idx = t + r * 256;
        int tok = idx >> 5, d = idx & 31;
        qS[tok][d] = qbuf[((size_t)b * N_ + n0 + tok) * CF_ + h * HD_ + d];
    }
    if (t < 128) {
        int n = n0 + t;
        float ra = (float)(n >> 6), cb = (float)(n & 63);
        float aa = (PI2F * ra) / 64.0f;
        float ab = (PI2F * cb) / 64.0f;
        tS[t][0] = cosf(aa); tS[t][1] = sinf(aa);
        tS[t][2] = cosf(ab); tS[t][3] = sinf(ab);
    }
    __syncthreads();
    if (t < 128) {
        float s = 0.f;
        for (int f = 0; f < 128; f++) s += qS[t][f & 31] * tS[t][f >> 5] * ksS[f];
        zS[t] = abs_clamp(1.f / (s + EPS_));
    }
    __syncthreads();

    int tx = t & 7, ty = t >> 3;    // d = tx*4.., tokens ty*4..
    float acc[4][4];
#pragma unroll
    for (int u = 0; u < 4; u++)
#pragma unroll
        for (int w = 0; w < 4; w++) acc[u][w] = 0.f;

#pragma unroll
    for (int ti = 0; ti < 4; ti++) {
        float tr0 = tS[ty * 4 + 0][ti];
        float tr1 = tS[ty * 4 + 1][ti];
        float tr2 = tS[ty * 4 + 2][ti];
        float tr3 = tS[ty * 4 + 3][ti];
        for (int dd = 0; dd < 32; dd++) {
            int f = ti * 32 + dd;
            float4 kvv = *(const float4*)&kvS[f][tx * 4];
            float q0 = qS[ty * 4 + 0][dd] * tr0;
            float q1 = qS[ty * 4 + 1][dd] * tr1;
            float q2 = qS[ty * 4 + 2][dd] * tr2;
            float q3 = qS[ty * 4 + 3][dd] * tr3;
            acc[0][0] += q0 * kvv.x; acc[0][1] += q0 * kvv.y; acc[0][2] += q0 * kvv.z; acc[0][3] += q0 * kvv.w;
            acc[1][0] += q1 * kvv.x; acc[1][1] += q1 * kvv.y; acc[1][2] += q1 * kvv.z; acc[1][3] += q1 * kvv.w;
            acc[2][0] += q2 * kvv.x; acc[2][1] += q2 * kvv.y; acc[2][2] += q2 * kvv.z; acc[2][3] += q2 * kvv.w;
            acc[3][0] += q3 * kvv.x; acc[3][1] += q3 * kvv.y; acc[3][2] += q3 * kvv.z; acc[3][3] += q3 * kvv.w;
        }
    }

#pragma unroll
    for (int u = 0; u < 4; u++) {
        int tok = ty * 4 + u;
        float z = zS[tok];
        float4 o;
        o.x = abs_clamp(abs_clamp(acc[u][0]) * z);
        o.y = abs_clamp(abs_clamp(acc[u][1]) * z);
        o.z = abs_clamp(abs_clamp(acc[u][2]) * z);
        o.w = abs_clamp(abs_clamp(acc[u][3]) * z);
        *(float4*)&qbuf[((size_t)b * N_ + n0 + tok) * CF_ + h * HD_ + tx * 4] = o;
    }
}

// ---------------------------------------------------------------- output projection + SE gating
__global__ __launch_bounds__(256) void out_gemm(const float* __restrict__ A,   // [M x 256] out_attn
                                                const float* __restrict__ Wo,  // [512 x 256]
                                                const float* __restrict__ bo,
                                                const float* __restrict__ sg,  // [B x 512] gate
                                                float* __restrict__ outp) {
    __shared__ float As[16][132];
    __shared__ float Bs[16][132];
    int t = threadIdx.x;
    int bm = blockIdx.x;        // 0..511
    int nc0 = blockIdx.y * 128; // 0..3 -> 512 cols

    int lr = t >> 1;
    int lc = (t & 1) * 8;
    const float* Ap = A + ((size_t)bm * 128 + lr) * CF_ + lc;
    const float* Wp = Wo + ((size_t)(nc0 + lr)) * CF_ + lc;

    float acc[2][2][4][4];
#pragma unroll
    for (int i = 0; i < 2; i++)
#pragma unroll
        for (int j = 0; j < 2; j++)
#pragma unroll
            for (int u = 0; u < 4; u++)
#pragma unroll
                for (int w = 0; w < 4; w++) acc[i][j][u][w] = 0.f;

    int tx = t & 15, ty = t >> 4;

    for (int k0 = 0; k0 < CF_; k0 += 16) {
        float4 a0 = *(const float4*)(Ap + k0);
        float4 a1 = *(const float4*)(Ap + k0 + 4);
        float4 b0 = *(const float4*)(Wp + k0);
        float4 b1 = *(const float4*)(Wp + k0 + 4);
        __syncthreads();
        As[lc + 0][lr] = a0.x; As[lc + 1][lr] = a0.y; As[lc + 2][lr] = a0.z; As[lc + 3][lr] = a0.w;
        As[lc + 4][lr] = a1.x; As[lc + 5][lr] = a1.y; As[lc + 6][lr] = a1.z; As[lc + 7][lr] = a1.w;
        Bs[lc + 0][lr] = b0.x; Bs[lc + 1][lr] = b0.y; Bs[lc + 2][lr] = b0.z; Bs[lc + 3][lr] = b0.w;
        Bs[lc + 4][lr] = b1.x; Bs[lc + 5][lr] = b1.y; Bs[lc + 6][lr] = b1.z; Bs[lc + 7][lr] = b1.w;
        __syncthreads();
#pragma unroll
        for (int kk = 0; kk < 16; kk++) {
            float4 a0v = *(const float4*)&As[kk][ty * 4];
            float4 a1v = *(const float4*)&As[kk][ty * 4 + 64];
            float4 b0v = *(const float4*)&Bs[kk][tx * 4];
            float4 b1v = *(const float4*)&Bs[kk][tx * 4 + 64];
            float av[2][4] = {{a0v.x, a0v.y, a0v.z, a0v.w}, {a1v.x, a1v.y, a1v.z, a1v.w}};
            float bv2[2][4] = {{b0v.x, b0v.y, b0v.z, b0v.w}, {b1v.x, b1v.y, b1v.z, b1v.w}};
#pragma unroll
            for (int i = 0; i < 2; i++)
#pragma unroll
                for (int u = 0; u < 4; u++)
#pragma unroll
                    for (int j = 0; j < 2; j++)
#pragma unroll
                        for (int w = 0; w < 4; w++) acc[i][j][u][w] += av[i][u] * bv2[j][w];
        }
    }

    int bidx = (bm * 128) >> 12;   // batch index (128-row tiles never straddle a batch)
#pragma unroll
    for (int i = 0; i < 2; i++)
#pragma unroll
        for (int u = 0; u < 4; u++) {
            size_t m = (size_t)bm * 128 + i * 64 + ty * 4 + u;
#pragma unroll
            for (int j = 0; j < 2; j++) {
                int c0 = nc0 + j * 64 + tx * 4;
                float4 bb = *(const float4*)(bo + c0);
                float4 gg = *(const float4*)(sg + (size_t)bidx * C_ + c0);
                float4 o;
                o.x = abs_clamp(abs_clamp(acc[i][j][u][0] + bb.x) * (1.f + gg.x));
                o.y = abs_clamp(abs_clamp(acc[i][j][u][1] + bb.y) * (1.f + gg.y));
                o.z = abs_clamp(abs_clamp(acc[i][j][u][2] + bb.z) * (1.f + gg.z));
                o.w = abs_clamp(abs_clamp(acc[i][j][u][3] + bb.w) * (1.f + gg.w));
                *(float4*)(outp + m * C_ + c0) = o;
            }
        }
}

// ----------------------------------------------------------------
extern "C" void kernel_launch(void* const* d_in, const int* in_sizes, int n_in,
                              void* d_out, int out_size, void* d_ws, size_t ws_size,
                              hipStream_t stream) {
    (void)in_sizes; (void)n_in; (void)out_size; (void)ws_size;
    const float* query = (const float*)d_in[0];
    const float* Wq  = (const float*)d_in[1];
    const float* bq  = (const float*)d_in[2];
    const float* Wk  = (const float*)d_in[3];
    const float* bk  = (const float*)d_in[4];
    const float* Wv  = (const float*)d_in[5];
    const float* bv  = (const float*)d_in[6];
    const float* Wo  = (const float*)d_in[7];
    const float* bo  = (const float*)d_in[8];
    const float* Wse1 = (const float*)d_in[9];
    const float* Wse2 = (const float*)d_in[10];
    float* out = (float*)d_out;

    float* ws  = (float*)d_ws;
    float* qb  = ws;                                   // [B*N*256] q, then out_attn (in-place)
    float* kb  = qb  + (size_t)B_ * N_ * CF_;          // [B*N*256]
    float* vb  = kb  + (size_t)B_ * N_ * CF_;          // [B*N*256]
    float* kvb = vb  + (size_t)B_ * N_ * CF_;          // [B*NH*128*32]
    float* ksb = kvb + (size_t)B_ * NH_ * FHD_ * HD_;  // [B*NH*128]
    float* ssb = ksb + (size_t)B_ * NH_ * FHD_;        // [B*512]
    float* sgb = ssb + (size_t)B_ * C_;                // [B*512]

    // zero the atomic accumulators (kvb, ksb, ssb are contiguous)
    size_t zbytes = ((size_t)B_ * NH_ * FHD_ * HD_ + (size_t)B_ * NH_ * FHD_ + (size_t)B_ * C_) * sizeof(float);
    hipMemsetAsync(kvb, 0, zbytes, stream);

    se_sum_kernel<<<dim3(B_, 16), 256, 0, stream>>>(query, ssb);
    se_gate_kernel<<<B_, 256, 0, stream>>>(ssb, Wse1, Wse2, sgb);
    qkv_gemm<<<dim3(512, 6), 256, 0, stream>>>(query, Wq, bq, Wk, bk, Wv, bv, qb, kb, vb);
    kv_kernel<<<dim3(8, NH_, B_), 256, 0, stream>>>(kb, vb, kvb, ksb);
    attn_kernel<<<dim3(32, NH_, B_), 256, 0, stream>>>(qb, kvb, ksb);
    out_gemm<<<dim3(512, 4), 256, 0, stream>>>(qb, Wo, bo, sgb, out);
}

// Round 2
// 1004.955 us; speedup vs baseline: 1.4363x; 1.4363x over previous
//
#include <hip/hip_runtime.h>
#include <math.h>

#define B_   16
#define N_   4096
#define C_   512
#define CF_  256
#define NH_  8
#define HD_  32
#define FHD_ 128
#define EPS_ 1e-4f
#define PI2F 1.5707963267948966f

typedef __bf16 bf16x8 __attribute__((ext_vector_type(8)));
typedef float f32x4 __attribute__((ext_vector_type(4)));
typedef unsigned short u16x8 __attribute__((ext_vector_type(8)));
typedef unsigned short u16x4 __attribute__((ext_vector_type(4)));

__device__ __forceinline__ float abs_clamp(float t) {
    float a = fminf(fmaxf(fabsf(t), 1e-4f), 1e4f);
    return t > 0.f ? a : (t < 0.f ? -a : 0.f);
}
__device__ __forceinline__ unsigned short f2bf(float x) {
    union { float f; unsigned u; } v; v.f = x;
    unsigned r = v.u + 0x7FFFu + ((v.u >> 16) & 1u);
    return (unsigned short)(r >> 16);
}
__device__ __forceinline__ float bf2f(unsigned short h) {
    union { unsigned u; float f; } v; v.u = ((unsigned)h) << 16;
    return v.f;
}
__device__ __forceinline__ void gld16(const void* g, void* l) {
    __builtin_amdgcn_global_load_lds(
        (const __attribute__((address_space(1))) void*)g,
        (__attribute__((address_space(3))) void*)l, 16, 0, 0);
}

// ---------------------------------------------------------------- SE: mean over tokens
__global__ __launch_bounds__(256) void se_sum_kernel(const float* __restrict__ q,
                                                     float* __restrict__ sesum) {
    int b = blockIdx.x, chunk = blockIdx.y;
    int c = threadIdx.x;
    const float* p = q + ((size_t)b * N_ + (size_t)chunk * 256) * C_;
    float a0 = 0.f, a1 = 0.f;
    for (int n = 0; n < 256; n++) {
        a0 += p[(size_t)n * C_ + c];
        a1 += p[(size_t)n * C_ + c + 256];
    }
    atomicAdd(&sesum[b * C_ + c], a0);
    atomicAdd(&sesum[b * C_ + c + 256], a1);
}

// ---------------------------------------------------------------- SE: 2-layer MLP + sigmoid
__global__ __launch_bounds__(256) void se_gate_kernel(const float* __restrict__ sesum,
                                                      const float* __restrict__ Wse1,
                                                      const float* __restrict__ Wse2,
                                                      float* __restrict__ segate) {
    __shared__ float sm[C_];
    __shared__ float hm[C_ / 2];
    int b = blockIdx.x, t = threadIdx.x;
    sm[t]       = sesum[b * C_ + t]       * (1.f / N_);
    sm[t + 256] = sesum[b * C_ + t + 256] * (1.f / N_);
    __syncthreads();
    {
        const float* w = Wse1 + (size_t)t * C_;
        float acc = 0.f;
        for (int c2 = 0; c2 < C_; c2++) acc += sm[c2] * w[c2];
        hm[t] = fmaxf(acc, 0.f);
    }
    __syncthreads();
    for (int r = 0; r < 2; r++) {
        int c2 = t + r * 256;
        const float* w2 = Wse2 + (size_t)c2 * (C_ / 2);
        float a2 = 0.f;
        for (int j = 0; j < C_ / 2; j++) a2 += hm[j] * w2[j];
        segate[b * C_ + c2] = 1.f / (1.f + expf(-a2));
    }
}

// ---------------------------------------------------------------- weight split to bf16 hi/lo
__global__ __launch_bounds__(256) void convert_w(const float* __restrict__ Wq,
                                                 const float* __restrict__ Wk,
                                                 const float* __restrict__ Wv,
                                                 const float* __restrict__ Wo,
                                                 unsigned short* __restrict__ wcat_hi,
                                                 unsigned short* __restrict__ wcat_lo,
                                                 unsigned short* __restrict__ wo_hi,
                                                 unsigned short* __restrict__ wo_lo) {
    int i = blockIdx.x * 256 + threadIdx.x;   // grid 2048 blocks -> 524288 threads
    if (i < 768 * 512) {
        int r = i >> 9, c = i & 511;
        float w = (r < 256) ? Wq[(size_t)r * 512 + c]
                : (r < 512) ? Wk[(size_t)(r - 256) * 512 + c]
                            : Wv[(size_t)(r - 512) * 512 + c];
        unsigned short h = f2bf(w);
        wcat_hi[i] = h;
        wcat_lo[i] = f2bf(w - bf2f(h));
    } else {
        int j = i - 768 * 512;                 // < 512*256
        float w = Wo[j];
        unsigned short h = f2bf(w);
        wo_hi[j] = h;
        wo_lo[j] = f2bf(w - bf2f(h));
    }
}

// ---------------------------------------------------------------- split-bf16 MFMA GEMM
// C[m,n] = A[m,:] . B[n,:]  via  Ah*Bh + Ah*Bl + Al*Bh  (fp32-equivalent)
// MODE 0: A = query fp32 (convert in staging), B = wcat [768,512], out q/k/v (+bias, relu)
// MODE 1: A = ohi/olo bf16 [M,256] via global_load_lds, B = wo [512,256], out (+bo, clamp, SE)
template <int MODE>
__global__ __launch_bounds__(256) void gemm_mfma(
    const float* __restrict__ Afp,
    const unsigned short* __restrict__ Ahi, const unsigned short* __restrict__ Alo,
    const unsigned short* __restrict__ Bhi, const unsigned short* __restrict__ Blo,
    const float* __restrict__ bias0, const float* __restrict__ bias1,
    const float* __restrict__ bias2, const float* __restrict__ sg,
    float* __restrict__ O0, float* __restrict__ O1, float* __restrict__ O2) {
    constexpr int K = (MODE == 0) ? 512 : 256;
    constexpr int NITER = K / 32;

    __shared__ __align__(16) unsigned short As[2][128 * 32];
    __shared__ __align__(16) unsigned short Bs[2][128 * 32];

    const int t = threadIdx.x;
    const int bx = blockIdx.x;
    const int Mb = blockIdx.y * 128;
    const int nrow0 = bx * 128;

    const int lane = t & 63;
    const int wv = t >> 6;
    const int mq = (wv >> 1) * 64;
    const int nq = (wv & 1) * 64;
    const int mrow = lane & 15;
    const int kq = lane >> 4;
    const int fragoff = mrow * 32 + ((kq ^ ((mrow >> 1) & 3)) * 8);

    // ---- B staging pointers (2 chunks per half per thread, XOR chunk swizzle)
    const unsigned char* bsrc[4];
    unsigned short* bdst[4];
    {
        int cid0 = t, cid1 = t + 256;
        int m0 = cid0 >> 2, c0 = (cid0 & 3) ^ ((m0 >> 1) & 3);
        int m1 = cid1 >> 2, c1 = (cid1 & 3) ^ ((m1 >> 1) & 3);
        bsrc[0] = (const unsigned char*)(Bhi + (size_t)(nrow0 + m0) * K + c0 * 8);
        bsrc[1] = (const unsigned char*)(Bhi + (size_t)(nrow0 + m1) * K + c1 * 8);
        bsrc[2] = (const unsigned char*)(Blo + (size_t)(nrow0 + m0) * K + c0 * 8);
        bsrc[3] = (const unsigned char*)(Blo + (size_t)(nrow0 + m1) * K + c1 * 8);
        bdst[0] = &Bs[0][cid0 * 8];
        bdst[1] = &Bs[0][cid1 * 8];
        bdst[2] = &Bs[1][cid0 * 8];
        bdst[3] = &Bs[1][cid1 * 8];
    }
    // ---- A staging pointers
    const unsigned char* asrc[4];
    unsigned short* adst[4];
    const float* afp_src = nullptr;
    unsigned short *adst_h0 = nullptr, *adst_h1 = nullptr, *adst_l0 = nullptr, *adst_l1 = nullptr;
    if (MODE == 1) {
        int cid0 = t, cid1 = t + 256;
        int m0 = cid0 >> 2, c0 = (cid0 & 3) ^ ((m0 >> 1) & 3);
        int m1 = cid1 >> 2, c1 = (cid1 & 3) ^ ((m1 >> 1) & 3);
        asrc[0] = (const unsigned char*)(Ahi + (size_t)(Mb + m0) * K + c0 * 8);
        asrc[1] = (const unsigned char*)(Ahi + (size_t)(Mb + m1) * K + c1 * 8);
        asrc[2] = (const unsigned char*)(Alo + (size_t)(Mb + m0) * K + c0 * 8);
        asrc[3] = (const unsigned char*)(Alo + (size_t)(Mb + m1) * K + c1 * 8);
        adst[0] = &As[0][cid0 * 8];
        adst[1] = &As[0][cid1 * 8];
        adst[2] = &As[1][cid0 * 8];
        adst[3] = &As[1][cid1 * 8];
    } else {
        int m0 = t >> 1, h2 = t & 1, sm = (m0 >> 1) & 3;
        afp_src = Afp + (size_t)(Mb + m0) * C_ + h2 * 16;
        adst_h0 = &As[0][m0 * 32 + (((2 * h2) ^ sm) * 8)];
        adst_h1 = &As[0][m0 * 32 + (((2 * h2 + 1) ^ sm) * 8)];
        adst_l0 = &As[1][m0 * 32 + (((2 * h2) ^ sm) * 8)];
        adst_l1 = &As[1][m0 * 32 + (((2 * h2 + 1) ^ sm) * 8)];
    }

    f32x4 acc[4][4];
#pragma unroll
    for (int mi = 0; mi < 4; mi++)
#pragma unroll
        for (int ni = 0; ni < 4; ni++) acc[mi][ni] = (f32x4){0.f, 0.f, 0.f, 0.f};

#pragma unroll 1
    for (int it = 0; it < NITER; ++it) {
        __syncthreads();
        if (MODE == 0) {
            const float* s = afp_src + it * 32;
            float va[16] __attribute__((aligned(16)));
            *(float4*)(va + 0) = *(const float4*)(s + 0);
            *(float4*)(va + 4) = *(const float4*)(s + 4);
            *(float4*)(va + 8) = *(const float4*)(s + 8);
            *(float4*)(va + 12) = *(const float4*)(s + 12);
            unsigned short hsv[16] __attribute__((aligned(16)));
            unsigned short lsv[16] __attribute__((aligned(16)));
#pragma unroll
            for (int ii = 0; ii < 16; ii++) {
                unsigned short h = f2bf(va[ii]);
                hsv[ii] = h;
                lsv[ii] = f2bf(va[ii] - bf2f(h));
            }
            *(u16x8*)adst_h0 = *(u16x8*)(hsv + 0);
            *(u16x8*)adst_h1 = *(u16x8*)(hsv + 8);
            *(u16x8*)adst_l0 = *(u16x8*)(lsv + 0);
            *(u16x8*)adst_l1 = *(u16x8*)(lsv + 8);
        } else {
            gld16(asrc[0] + it * 64, adst[0]);
            gld16(asrc[1] + it * 64, adst[1]);
            gld16(asrc[2] + it * 64, adst[2]);
            gld16(asrc[3] + it * 64, adst[3]);
        }
        gld16(bsrc[0] + it * 64, bdst[0]);
        gld16(bsrc[1] + it * 64, bdst[1]);
        gld16(bsrc[2] + it * 64, bdst[2]);
        gld16(bsrc[3] + it * 64, bdst[3]);
        __syncthreads();

        bf16x8 ah[4], al[4], bh[4], bl[4];
#pragma unroll
        for (int mi = 0; mi < 4; mi++) {
            int off = (mq + mi * 16) * 32 + fragoff;
            ah[mi] = *(const bf16x8*)&As[0][off];
            al[mi] = *(const bf16x8*)&As[1][off];
        }
#pragma unroll
        for (int ni = 0; ni < 4; ni++) {
            int off = (nq + ni * 16) * 32 + fragoff;
            bh[ni] = *(const bf16x8*)&Bs[0][off];
            bl[ni] = *(const bf16x8*)&Bs[1][off];
        }
#pragma unroll
        for (int mi = 0; mi < 4; mi++)
#pragma unroll
            for (int ni = 0; ni < 4; ni++) {
                f32x4 a = acc[mi][ni];
                a = __builtin_amdgcn_mfma_f32_16x16x32_bf16(ah[mi], bh[ni], a, 0, 0, 0);
                a = __builtin_amdgcn_mfma_f32_16x16x32_bf16(ah[mi], bl[ni], a, 0, 0, 0);
                a = __builtin_amdgcn_mfma_f32_16x16x32_bf16(al[mi], bh[ni], a, 0, 0, 0);
                acc[mi][ni] = a;
            }
    }

    if (MODE == 0) {
        int mat = bx >> 1;
        int nc0 = (bx & 1) * 128;
        const float* bias = (mat == 0) ? bias0 : (mat == 1) ? bias1 : bias2;
        float* O = (mat == 0) ? O0 : (mat == 1) ? O1 : O2;
#pragma unroll
        for (int ni = 0; ni < 4; ni++) {
            int cg = nc0 + nq + ni * 16 + mrow;
            float bb = bias[cg];
#pragma unroll
            for (int mi = 0; mi < 4; mi++)
#pragma unroll
                for (int r = 0; r < 4; r++) {
                    int m = Mb + mq + mi * 16 + kq * 4 + r;
                    float v2 = acc[mi][ni][r] + bb;
                    if (mat < 2) v2 = fmaxf(v2, 0.f);
                    O[(size_t)m * CF_ + cg] = v2;
                }
        }
    } else {
        int b = Mb >> 12;
#pragma unroll
        for (int ni = 0; ni < 4; ni++) {
            int cg = nrow0 + nq + ni * 16 + mrow;
            float bb = bias0[cg];
            float gv = sg[b * C_ + cg];
#pragma unroll
            for (int mi = 0; mi < 4; mi++)
#pragma unroll
                for (int r = 0; r < 4; r++) {
                    int m = Mb + mq + mi * 16 + kq * 4 + r;
                    float v2 = abs_clamp(acc[mi][ni][r] + bb);
                    v2 = abs_clamp(v2 * (1.f + gv));
                    O0[(size_t)m * C_ + cg] = v2;
                }
        }
    }
}

// ---------------------------------------------------------------- kv state + k_sum
__global__ __launch_bounds__(256) void kv_kernel(const float* __restrict__ kin,
                                                 const float* __restrict__ vin,
                                                 float* __restrict__ kvout,
                                                 float* __restrict__ ksum) {
    int chunk = blockIdx.x;
    int h = blockIdx.y, b = blockIdx.z;
    int t = threadIdx.x;
    __shared__ float kb[32][32];
    __shared__ float vb[32][32];
    __shared__ float tb[32][4];

    int i = t & 15, j = t >> 4;
    float acc[4][2][2];
#pragma unroll
    for (int a = 0; a < 4; a++)
#pragma unroll
        for (int x = 0; x < 2; x++)
#pragma unroll
            for (int y = 0; y < 2; y++) acc[a][x][y] = 0.f;
    float ksacc = 0.f;

    for (int s = 0; s < 16; s++) {
        int n0 = chunk * 512 + s * 32;
        __syncthreads();
#pragma unroll
        for (int r = 0; r < 4; r++) {
            int idx = t + r * 256;
            int tok = idx >> 5, d = idx & 31;
            size_t g = ((size_t)b * N_ + n0 + tok) * CF_ + h * HD_ + d;
            kb[tok][d] = kin[g];
            vb[tok][d] = vin[g];
        }
        if (t < 32) {
            int n = n0 + t;
            float ra = (float)(n >> 6), cb = (float)(n & 63);
            float aa = (PI2F * ra) / 64.0f;
            float ab = (PI2F * cb) / 64.0f;
            tb[t][0] = cosf(aa); tb[t][1] = sinf(aa);
            tb[t][2] = cosf(ab); tb[t][3] = sinf(ab);
        }
        __syncthreads();
        for (int n = 0; n < 32; n++) {
            float t0 = tb[n][0], t1 = tb[n][1], t2 = tb[n][2], t3 = tb[n][3];
            float ka = kb[n][2 * i], ka2 = kb[n][2 * i + 1];
            float va = vb[n][2 * j], va2 = vb[n][2 * j + 1];
            float p;
            p = ka * t0;  acc[0][0][0] += p * va; acc[0][0][1] += p * va2;
            p = ka2 * t0; acc[0][1][0] += p * va; acc[0][1][1] += p * va2;
            p = ka * t1;  acc[1][0][0] += p * va; acc[1][0][1] += p * va2;
            p = ka2 * t1; acc[1][1][0] += p * va; acc[1][1][1] += p * va2;
            p = ka * t2;  acc[2][0][0] += p * va; acc[2][0][1] += p * va2;
            p = ka2 * t2; acc[2][1][0] += p * va; acc[2][1][1] += p * va2;
            p = ka * t3;  acc[3][0][0] += p * va; acc[3][0][1] += p * va2;
            p = ka2 * t3; acc[3][1][0] += p * va; acc[3][1][1] += p * va2;
        }
        if (t < 128) {
            int ti = t >> 5, dd = t & 31;
            for (int n = 0; n < 32; n++) ksacc += tb[n][ti] * kb[n][dd];
        }
    }

    float* kvp = kvout + ((size_t)(b * NH_ + h)) * FHD_ * HD_;
#pragma unroll
    for (int a = 0; a < 4; a++)
#pragma unroll
        for (int x = 0; x < 2; x++)
#pragma unroll
            for (int y = 0; y < 2; y++)
                atomicAdd(&kvp[(size_t)(a * 32 + 2 * i + x) * HD_ + 2 * j + y], acc[a][x][y]);
    if (t < 128) atomicAdd(&ksum[(size_t)(b * NH_ + h) * FHD_ + t], ksacc);
}

// ---------------------------------------------------------------- attention lookup -> bf16 hi/lo
__global__ __launch_bounds__(256) void attn_kernel(const float* __restrict__ qbuf,
                                                   const float* __restrict__ kvin,
                                                   const float* __restrict__ ksum,
                                                   unsigned short* __restrict__ ohi,
                                                   unsigned short* __restrict__ olo) {
    int chunk = blockIdx.x;
    int h = blockIdx.y, b = blockIdx.z;
    int t = threadIdx.x;
    __shared__ float kvS[128][32];
    __shared__ float qS[128][33];
    __shared__ float tS[128][4];
    __shared__ float ksS[128];
    __shared__ float zS[128];
    int n0 = chunk * 128;

    const float* kvp = kvin + ((size_t)(b * NH_ + h)) * FHD_ * HD_;
#pragma unroll
    for (int r = 0; r < 16; r++) {
        int idx = t + r * 256;
        (&kvS[0][0])[idx] = abs_clamp(kvp[idx]);
    }
    if (t < 128) ksS[t] = ksum[(size_t)(b * NH_ + h) * FHD_ + t];
#pragma unroll
    for (int r = 0; r < 16; r++) {
        int idx = t + r * 256;
        int tok = idx >> 5, d = idx & 31;
        qS[tok][d] = qbuf[((size_t)b * N_ + n0 + tok) * CF_ + h * HD_ + d];
    }
    if (t < 128) {
        int n = n0 + t;
        float ra = (float)(n >> 6), cb = (float)(n & 63);
        float aa = (PI2F * ra) / 64.0f;
        float ab = (PI2F * cb) / 64.0f;
        tS[t][0] = cosf(aa); tS[t][1] = sinf(aa);
        tS[t][2] = cosf(ab); tS[t][3] = sinf(ab);
    }
    __syncthreads();
    if (t < 128) {
        float s = 0.f;
        for (int f = 0; f < 128; f++) s += qS[t][f & 31] * tS[t][f >> 5] * ksS[f];
        zS[t] = abs_clamp(1.f / (s + EPS_));
    }
    __syncthreads();

    int tx = t & 7, ty = t >> 3;
    float acc[4][4];
#pragma unroll
    for (int u = 0; u < 4; u++)
#pragma unroll
        for (int w = 0; w < 4; w++) acc[u][w] = 0.f;

#pragma unroll
    for (int ti = 0; ti < 4; ti++) {
        float tr0 = tS[ty * 4 + 0][ti];
        float tr1 = tS[ty * 4 + 1][ti];
        float tr2 = tS[ty * 4 + 2][ti];
        float tr3 = tS[ty * 4 + 3][ti];
        for (int dd = 0; dd < 32; dd++) {
            int f = ti * 32 + dd;
            float4 kvv = *(const float4*)&kvS[f][tx * 4];
            float q0 = qS[ty * 4 + 0][dd] * tr0;
            float q1 = qS[ty * 4 + 1][dd] * tr1;
            float q2 = qS[ty * 4 + 2][dd] * tr2;
            float q3 = qS[ty * 4 + 3][dd] * tr3;
            acc[0][0] += q0 * kvv.x; acc[0][1] += q0 * kvv.y; acc[0][2] += q0 * kvv.z; acc[0][3] += q0 * kvv.w;
            acc[1][0] += q1 * kvv.x; acc[1][1] += q1 * kvv.y; acc[1][2] += q1 * kvv.z; acc[1][3] += q1 * kvv.w;
            acc[2][0] += q2 * kvv.x; acc[2][1] += q2 * kvv.y; acc[2][2] += q2 * kvv.z; acc[2][3] += q2 * kvv.w;
            acc[3][0] += q3 * kvv.x; acc[3][1] += q3 * kvv.y; acc[3][2] += q3 * kvv.z; acc[3][3] += q3 * kvv.w;
        }
    }

#pragma unroll
    for (int u = 0; u < 4; u++) {
        int tok = ty * 4 + u;
        float z = zS[tok];
        float ov[4];
        ov[0] = abs_clamp(abs_clamp(acc[u][0]) * z);
        ov[1] = abs_clamp(abs_clamp(acc[u][1]) * z);
        ov[2] = abs_clamp(abs_clamp(acc[u][2]) * z);
        ov[3] = abs_clamp(abs_clamp(acc[u][3]) * z);
        u16x4 hv, lv;
#pragma unroll
        for (int w = 0; w < 4; w++) {
            unsigned short hh = f2bf(ov[w]);
            hv[w] = hh;
            lv[w] = f2bf(ov[w] - bf2f(hh));
        }
        size_t base = ((size_t)b * N_ + n0 + tok) * CF_ + h * HD_ + tx * 4;
        *(u16x4*)&ohi[base] = hv;
        *(u16x4*)&olo[base] = lv;
    }
}

// ----------------------------------------------------------------
extern "C" void kernel_launch(void* const* d_in, const int* in_sizes, int n_in,
                              void* d_out, int out_size, void* d_ws, size_t ws_size,
                              hipStream_t stream) {
    (void)in_sizes; (void)n_in; (void)out_size; (void)ws_size;
    const float* query = (const float*)d_in[0];
    const float* Wq = (const float*)d_in[1];
    const float* bq = (const float*)d_in[2];
    const float* Wk = (const float*)d_in[3];
    const float* bk = (const float*)d_in[4];
    const float* Wv = (const float*)d_in[5];
    const float* bv = (const float*)d_in[6];
    const float* Wo = (const float*)d_in[7];
    const float* bo = (const float*)d_in[8];
    const float* Wse1 = (const float*)d_in[9];
    const float* Wse2 = (const float*)d_in[10];
    float* out = (float*)d_out;

    unsigned char* ws = (unsigned char*)d_ws;
    const size_t MB = 1024ull * 1024ull;
    float* qb = (float*)(ws + 0);                      // [65536,256] fp32, 64 MiB
    float* kb = (float*)(ws + 64 * MB);                // [65536,256] fp32, 64 MiB
    float* vb = (float*)(ws + 128 * MB);               // [65536,256] fp32, 64 MiB
    unsigned short* wcat_hi = (unsigned short*)(ws + 192 * MB);            // [768,512]
    unsigned short* wcat_lo = (unsigned short*)(ws + 192 * MB + 786432);
    unsigned short* wo_hi   = (unsigned short*)(ws + 192 * MB + 1572864); // [512,256]
    unsigned short* wo_lo   = (unsigned short*)(ws + 192 * MB + 1835008);
    float* kvb = (float*)(ws + 192 * MB + 2097152);    // [16,8,128,32] 2 MiB
    float* ksb = (float*)(ws + 194 * MB + 2097152);    // [16,8,128] 64 KiB
    float* ssb = (float*)(ws + 194 * MB + 2162688);    // [16,512] 32 KiB
    float* sgb = (float*)(ws + 194 * MB + 2195456);    // [16,512] 32 KiB
    // out_attn bf16 hi/lo alias the dead k buffer (kv_kernel completes before attn)
    unsigned short* ohi = (unsigned short*)(ws + 64 * MB);
    unsigned short* olo = (unsigned short*)(ws + 64 * MB + 32 * MB);

    // zero atomic accumulators: kvb, ksb, ssb are contiguous
    hipMemsetAsync(kvb, 0, 2097152 + 65536 + 32768, stream);

    convert_w<<<2048, 256, 0, stream>>>(Wq, Wk, Wv, Wo, wcat_hi, wcat_lo, wo_hi, wo_lo);
    se_sum_kernel<<<dim3(B_, 16), 256, 0, stream>>>(query, ssb);
    se_gate_kernel<<<B_, 256, 0, stream>>>(ssb, Wse1, Wse2, sgb);
    gemm_mfma<0><<<dim3(6, 512), 256, 0, stream>>>(query, nullptr, nullptr, wcat_hi, wcat_lo,
                                                   bq, bk, bv, nullptr, qb, kb, vb);
    kv_kernel<<<dim3(8, NH_, B_), 256, 0, stream>>>(kb, vb, kvb, ksb);
    attn_kernel<<<dim3(32, NH_, B_), 256, 0, stream>>>(qb, kvb, ksb, ohi, olo);
    gemm_mfma<1><<<dim3(4, 512), 256, 0, stream>>>(nullptr, ohi, olo, wo_hi, wo_lo,
                                                   bo, nullptr, nullptr, sgb, out, nullptr, nullptr);
}

// Round 3
// 701.739 us; speedup vs baseline: 2.0569x; 1.4321x over previous
//
#include <hip/hip_runtime.h>
#include <math.h>

#define B_   16
#define N_   4096
#define C_   512
#define CF_  256
#define NH_  8
#define HD_  32
#define FHD_ 128
#define EPS_ 1e-4f
#define PI2F 1.5707963267948966f

typedef __bf16 bf16x8 __attribute__((ext_vector_type(8)));
typedef float f32x4 __attribute__((ext_vector_type(4)));
typedef unsigned short u16x8 __attribute__((ext_vector_type(8)));
typedef unsigned short u16x4 __attribute__((ext_vector_type(4)));

__device__ __forceinline__ float abs_clamp(float t) {
    float a = fminf(fmaxf(fabsf(t), 1e-4f), 1e4f);
    return t > 0.f ? a : (t < 0.f ? -a : 0.f);
}
__device__ __forceinline__ unsigned short f2bf(float x) {
    union { float f; unsigned u; } v; v.f = x;
    unsigned r = v.u + 0x7FFFu + ((v.u >> 16) & 1u);
    return (unsigned short)(r >> 16);
}
__device__ __forceinline__ float bf2f(unsigned short h) {
    union { unsigned u; float f; } v; v.u = ((unsigned)h) << 16;
    return v.f;
}
__device__ __forceinline__ void gld16(const void* g, void* l) {
    __builtin_amdgcn_global_load_lds(
        (const __attribute__((address_space(1))) void*)g,
        (__attribute__((address_space(3))) void*)l, 16, 0, 0);
}

// ---------------------------------------------------------------- SE: mean over tokens
__global__ __launch_bounds__(256) void se_sum_kernel(const float* __restrict__ q,
                                                     float* __restrict__ sesum) {
    int b = blockIdx.x, chunk = blockIdx.y;
    int c = threadIdx.x;
    const float* p = q + ((size_t)b * N_ + (size_t)chunk * 256) * C_;
    float a0 = 0.f, a1 = 0.f;
    for (int n = 0; n < 256; n++) {
        a0 += p[(size_t)n * C_ + c];
        a1 += p[(size_t)n * C_ + c + 256];
    }
    atomicAdd(&sesum[b * C_ + c], a0);
    atomicAdd(&sesum[b * C_ + c + 256], a1);
}

// ---------------------------------------------------------------- SE: 2-layer MLP + sigmoid
__global__ __launch_bounds__(256) void se_gate_kernel(const float* __restrict__ sesum,
                                                      const float* __restrict__ Wse1,
                                                      const float* __restrict__ Wse2,
                                                      float* __restrict__ segate) {
    __shared__ float sm[C_];
    __shared__ float hm[C_ / 2];
    int b = blockIdx.x, t = threadIdx.x;
    sm[t]       = sesum[b * C_ + t]       * (1.f / N_);
    sm[t + 256] = sesum[b * C_ + t + 256] * (1.f / N_);
    __syncthreads();
    {
        const float* w = Wse1 + (size_t)t * C_;
        float acc = 0.f;
        for (int c2 = 0; c2 < C_; c2++) acc += sm[c2] * w[c2];
        hm[t] = fmaxf(acc, 0.f);
    }
    __syncthreads();
    for (int r = 0; r < 2; r++) {
        int c2 = t + r * 256;
        const float* w2 = Wse2 + (size_t)c2 * (C_ / 2);
        float a2 = 0.f;
        for (int j = 0; j < C_ / 2; j++) a2 += hm[j] * w2[j];
        segate[b * C_ + c2] = 1.f / (1.f + expf(-a2));
    }
}

// ---------------------------------------------------------------- weight split to bf16 hi/lo
__global__ __launch_bounds__(256) void convert_w(const float* __restrict__ Wq,
                                                 const float* __restrict__ Wk,
                                                 const float* __restrict__ Wv,
                                                 const float* __restrict__ Wo,
                                                 unsigned short* __restrict__ wcat_hi,
                                                 unsigned short* __restrict__ wcat_lo,
                                                 unsigned short* __restrict__ wo_hi,
                                                 unsigned short* __restrict__ wo_lo) {
    int i = blockIdx.x * 256 + threadIdx.x;
    if (i < 768 * 512) {
        int r = i >> 9, c = i & 511;
        float w = (r < 256) ? Wq[(size_t)r * 512 + c]
                : (r < 512) ? Wk[(size_t)(r - 256) * 512 + c]
                            : Wv[(size_t)(r - 512) * 512 + c];
        unsigned short h = f2bf(w);
        wcat_hi[i] = h;
        wcat_lo[i] = f2bf(w - bf2f(h));
    } else {
        int j = i - 768 * 512;
        float w = Wo[j];
        unsigned short h = f2bf(w);
        wo_hi[j] = h;
        wo_lo[j] = f2bf(w - bf2f(h));
    }
}

// ---------------------------------------------------------------- split-bf16 MFMA GEMM
template <int MODE>
__global__ __launch_bounds__(256) void gemm_mfma(
    const float* __restrict__ Afp,
    const unsigned short* __restrict__ Ahi, const unsigned short* __restrict__ Alo,
    const unsigned short* __restrict__ Bhi, const unsigned short* __restrict__ Blo,
    const float* __restrict__ bias0, const float* __restrict__ bias1,
    const float* __restrict__ bias2, const float* __restrict__ sg,
    float* __restrict__ O0, float* __restrict__ O1, float* __restrict__ O2) {
    constexpr int K = (MODE == 0) ? 512 : 256;
    constexpr int NITER = K / 32;

    __shared__ __align__(16) unsigned short As[2][128 * 32];
    __shared__ __align__(16) unsigned short Bs[2][128 * 32];

    const int t = threadIdx.x;
    const int bx = blockIdx.x;
    const int Mb = blockIdx.y * 128;
    const int nrow0 = bx * 128;

    const int lane = t & 63;
    const int wv = t >> 6;
    const int mq = (wv >> 1) * 64;
    const int nq = (wv & 1) * 64;
    const int mrow = lane & 15;
    const int kq = lane >> 4;
    const int fragoff = mrow * 32 + ((kq ^ ((mrow >> 1) & 3)) * 8);

    const unsigned char* bsrc[4];
    unsigned short* bdst[4];
    {
        int cid0 = t, cid1 = t + 256;
        int m0 = cid0 >> 2, c0 = (cid0 & 3) ^ ((m0 >> 1) & 3);
        int m1 = cid1 >> 2, c1 = (cid1 & 3) ^ ((m1 >> 1) & 3);
        bsrc[0] = (const unsigned char*)(Bhi + (size_t)(nrow0 + m0) * K + c0 * 8);
        bsrc[1] = (const unsigned char*)(Bhi + (size_t)(nrow0 + m1) * K + c1 * 8);
        bsrc[2] = (const unsigned char*)(Blo + (size_t)(nrow0 + m0) * K + c0 * 8);
        bsrc[3] = (const unsigned char*)(Blo + (size_t)(nrow0 + m1) * K + c1 * 8);
        bdst[0] = &Bs[0][cid0 * 8];
        bdst[1] = &Bs[0][cid1 * 8];
        bdst[2] = &Bs[1][cid0 * 8];
        bdst[3] = &Bs[1][cid1 * 8];
    }
    const unsigned char* asrc[4];
    unsigned short* adst[4];
    const float* afp_src = nullptr;
    unsigned short *adst_h0 = nullptr, *adst_h1 = nullptr, *adst_l0 = nullptr, *adst_l1 = nullptr;
    if (MODE == 1) {
        int cid0 = t, cid1 = t + 256;
        int m0 = cid0 >> 2, c0 = (cid0 & 3) ^ ((m0 >> 1) & 3);
        int m1 = cid1 >> 2, c1 = (cid1 & 3) ^ ((m1 >> 1) & 3);
        asrc[0] = (const unsigned char*)(Ahi + (size_t)(Mb + m0) * K + c0 * 8);
        asrc[1] = (const unsigned char*)(Ahi + (size_t)(Mb + m1) * K + c1 * 8);
        asrc[2] = (const unsigned char*)(Alo + (size_t)(Mb + m0) * K + c0 * 8);
        asrc[3] = (const unsigned char*)(Alo + (size_t)(Mb + m1) * K + c1 * 8);
        adst[0] = &As[0][cid0 * 8];
        adst[1] = &As[0][cid1 * 8];
        adst[2] = &As[1][cid0 * 8];
        adst[3] = &As[1][cid1 * 8];
    } else {
        int m0 = t >> 1, h2 = t & 1, sm = (m0 >> 1) & 3;
        afp_src = Afp + (size_t)(Mb + m0) * C_ + h2 * 16;
        adst_h0 = &As[0][m0 * 32 + (((2 * h2) ^ sm) * 8)];
        adst_h1 = &As[0][m0 * 32 + (((2 * h2 + 1) ^ sm) * 8)];
        adst_l0 = &As[1][m0 * 32 + (((2 * h2) ^ sm) * 8)];
        adst_l1 = &As[1][m0 * 32 + (((2 * h2 + 1) ^ sm) * 8)];
    }

    f32x4 acc[4][4];
#pragma unroll
    for (int mi = 0; mi < 4; mi++)
#pragma unroll
        for (int ni = 0; ni < 4; ni++) acc[mi][ni] = (f32x4){0.f, 0.f, 0.f, 0.f};

#pragma unroll 1
    for (int it = 0; it < NITER; ++it) {
        __syncthreads();
        if (MODE == 0) {
            const float* s = afp_src + it * 32;
            float va[16] __attribute__((aligned(16)));
            *(float4*)(va + 0) = *(const float4*)(s + 0);
            *(float4*)(va + 4) = *(const float4*)(s + 4);
            *(float4*)(va + 8) = *(const float4*)(s + 8);
            *(float4*)(va + 12) = *(const float4*)(s + 12);
            unsigned short hsv[16] __attribute__((aligned(16)));
            unsigned short lsv[16] __attribute__((aligned(16)));
#pragma unroll
            for (int ii = 0; ii < 16; ii++) {
                unsigned short h = f2bf(va[ii]);
                hsv[ii] = h;
                lsv[ii] = f2bf(va[ii] - bf2f(h));
            }
            *(u16x8*)adst_h0 = *(u16x8*)(hsv + 0);
            *(u16x8*)adst_h1 = *(u16x8*)(hsv + 8);
            *(u16x8*)adst_l0 = *(u16x8*)(lsv + 0);
            *(u16x8*)adst_l1 = *(u16x8*)(lsv + 8);
        } else {
            gld16(asrc[0] + it * 64, adst[0]);
            gld16(asrc[1] + it * 64, adst[1]);
            gld16(asrc[2] + it * 64, adst[2]);
            gld16(asrc[3] + it * 64, adst[3]);
        }
        gld16(bsrc[0] + it * 64, bdst[0]);
        gld16(bsrc[1] + it * 64, bdst[1]);
        gld16(bsrc[2] + it * 64, bdst[2]);
        gld16(bsrc[3] + it * 64, bdst[3]);
        __syncthreads();

        bf16x8 ah[4], al[4], bh[4], bl[4];
#pragma unroll
        for (int mi = 0; mi < 4; mi++) {
            int off = (mq + mi * 16) * 32 + fragoff;
            ah[mi] = *(const bf16x8*)&As[0][off];
            al[mi] = *(const bf16x8*)&As[1][off];
        }
#pragma unroll
        for (int ni = 0; ni < 4; ni++) {
            int off = (nq + ni * 16) * 32 + fragoff;
            bh[ni] = *(const bf16x8*)&Bs[0][off];
            bl[ni] = *(const bf16x8*)&Bs[1][off];
        }
#pragma unroll
        for (int mi = 0; mi < 4; mi++)
#pragma unroll
            for (int ni = 0; ni < 4; ni++) {
                f32x4 a = acc[mi][ni];
                a = __builtin_amdgcn_mfma_f32_16x16x32_bf16(ah[mi], bh[ni], a, 0, 0, 0);
                a = __builtin_amdgcn_mfma_f32_16x16x32_bf16(ah[mi], bl[ni], a, 0, 0, 0);
                a = __builtin_amdgcn_mfma_f32_16x16x32_bf16(al[mi], bh[ni], a, 0, 0, 0);
                acc[mi][ni] = a;
            }
    }

    if (MODE == 0) {
        int mat = bx >> 1;
        int nc0 = (bx & 1) * 128;
        const float* bias = (mat == 0) ? bias0 : (mat == 1) ? bias1 : bias2;
        float* O = (mat == 0) ? O0 : (mat == 1) ? O1 : O2;
#pragma unroll
        for (int ni = 0; ni < 4; ni++) {
            int cg = nc0 + nq + ni * 16 + mrow;
            float bb = bias[cg];
#pragma unroll
            for (int mi = 0; mi < 4; mi++)
#pragma unroll
                for (int r = 0; r < 4; r++) {
                    int m = Mb + mq + mi * 16 + kq * 4 + r;
                    float v2 = acc[mi][ni][r] + bb;
                    if (mat < 2) v2 = fmaxf(v2, 0.f);
                    O[(size_t)m * CF_ + cg] = v2;
                }
        }
    } else {
        int b = Mb >> 12;
#pragma unroll
        for (int ni = 0; ni < 4; ni++) {
            int cg = nrow0 + nq + ni * 16 + mrow;
            float bb = bias0[cg];
            float gv = sg[b * C_ + cg];
#pragma unroll
            for (int mi = 0; mi < 4; mi++)
#pragma unroll
                for (int r = 0; r < 4; r++) {
                    int m = Mb + mq + mi * 16 + kq * 4 + r;
                    float v2 = abs_clamp(acc[mi][ni][r] + bb);
                    v2 = abs_clamp(v2 * (1.f + gv));
                    O0[(size_t)m * C_ + cg] = v2;
                }
        }
    }
}

// ---------------------------------------------------------------- kv state + k_sum via MFMA
// Per (b,h): C[f=128][d=32] = sum_n trig(f>>5,n)*k[n,f&31] * v[n,d], ksum via ones-column.
// A[f][tok] staged transposed (trig applied, split bf16); B rows 0..31 = v^T, row 32 = ones.
__global__ __launch_bounds__(256) void kv_mfma_kernel(const float* __restrict__ kin,
                                                      const float* __restrict__ vin,
                                                      float* __restrict__ kvout,
                                                      float* __restrict__ ksum) {
    __shared__ __align__(16) unsigned short Ah[128 * 64];
    __shared__ __align__(16) unsigned short Al[128 * 64];
    __shared__ __align__(16) unsigned short Bh[48 * 64];
    __shared__ __align__(16) unsigned short Bl[48 * 64];

    const int t = threadIdx.x;
    const int c8 = blockIdx.x;           // 512-token slab
    const int h = blockIdx.y, b = blockIdx.z;
    const int dp = t & 31;               // channel within head (serves k and v)
    const int octet = t >> 5;            // 0..7 -> tokens octet*8..+7

    // constant B rows 32..47: row 32 = ones, rest zero (written once)
    {
        int r = 32 + (t & 15);
        int oc = (t >> 4) & 7;
        int bufsel = t >> 7;
        int off = r * 64 + (((oc ^ ((r >> 3) & 7)) & 7) * 8);
        unsigned short fill = (r == 32 && bufsel == 0) ? (unsigned short)0x3F80 : (unsigned short)0;
        u16x8 z = {fill, fill, fill, fill, fill, fill, fill, fill};
        if (bufsel == 0) *(u16x8*)&Bh[off] = z;
        else             *(u16x8*)&Bl[off] = z;
    }

    // per-thread column trig (token within chunk = octet*8+i, constant across chunks)
    float cbv[8], sbv[8];
#pragma unroll
    for (int i = 0; i < 8; i++) {
        float ang = (PI2F / 64.f) * (float)(octet * 8 + i);
        cbv[i] = cosf(ang);
        sbv[i] = sinf(ang);
    }

    const int lane = t & 63;
    const int wv = t >> 6;
    const int mrow = lane & 15;
    const int kq = lane >> 4;

    f32x4 acc[2][3];
#pragma unroll
    for (int mi = 0; mi < 2; mi++)
#pragma unroll
        for (int ni = 0; ni < 3; ni++) acc[mi][ni] = (f32x4){0.f, 0.f, 0.f, 0.f};

    // pre-swizzled store offsets: A rows f = tvar*32+dp, B row dp
    int offA[4];
#pragma unroll
    for (int tvar = 0; tvar < 4; tvar++) {
        int f = tvar * 32 + dp;
        offA[tvar] = f * 64 + (((octet ^ ((f >> 3) & 7)) & 7) * 8);
    }
    const int offB = dp * 64 + (((octet ^ ((dp >> 3) & 7)) & 7) * 8);

#pragma unroll 1
    for (int ch = 0; ch < 8; ch++) {
        const int n0 = c8 * 512 + ch * 64;
        const int rrow = n0 >> 6;                 // row index constant per chunk
        float aang = (PI2F / 64.f) * (float)rrow;
        float ca = cosf(aang), sa = sinf(aang);

        // coalesced strided loads: 8 tokens, one channel
        const float* kp = kin + ((size_t)b * N_ + n0 + octet * 8) * CF_ + h * HD_ + dp;
        const float* vp = vin + ((size_t)b * N_ + n0 + octet * 8) * CF_ + h * HD_ + dp;
        float kvl[8], vvl[8];
#pragma unroll
        for (int i = 0; i < 8; i++) kvl[i] = kp[(size_t)i * CF_];
#pragma unroll
        for (int i = 0; i < 8; i++) vvl[i] = vp[(size_t)i * CF_];

        __syncthreads();   // previous chunk's fragment reads done

        // A rows: trig-scaled k, split hi/lo
#pragma unroll
        for (int tvar = 0; tvar < 4; tvar++) {
            u16x8 hv, lv;
#pragma unroll
            for (int i = 0; i < 8; i++) {
                float val = kvl[i] * (tvar == 0 ? ca : tvar == 1 ? sa : tvar == 2 ? cbv[i] : sbv[i]);
                unsigned short hh = f2bf(val);
                hv[i] = hh;
                lv[i] = f2bf(val - bf2f(hh));
            }
            *(u16x8*)&Ah[offA[tvar]] = hv;
            *(u16x8*)&Al[offA[tvar]] = lv;
        }
        // B row dp: v split hi/lo
        {
            u16x8 hv, lv;
#pragma unroll
            for (int i = 0; i < 8; i++) {
                unsigned short hh = f2bf(vvl[i]);
                hv[i] = hh;
                lv[i] = f2bf(vvl[i] - bf2f(hh));
            }
            *(u16x8*)&Bh[offB] = hv;
            *(u16x8*)&Bl[offB] = lv;
        }
        __syncthreads();

#pragma unroll
        for (int s = 0; s < 2; s++) {
            bf16x8 ah[2], al2[2], bh[3], bl[3];
            int koct = s * 4 + kq;
#pragma unroll
            for (int mi = 0; mi < 2; mi++) {
                int f = (wv * 2 + mi) * 16 + mrow;
                int off = f * 64 + (((koct ^ ((f >> 3) & 7)) & 7) * 8);
                ah[mi] = *(const bf16x8*)&Ah[off];
                al2[mi] = *(const bf16x8*)&Al[off];
            }
#pragma unroll
            for (int ni = 0; ni < 3; ni++) {
                int nr = ni * 16 + mrow;
                int off = nr * 64 + (((koct ^ ((nr >> 3) & 7)) & 7) * 8);
                bh[ni] = *(const bf16x8*)&Bh[off];
                bl[ni] = *(const bf16x8*)&Bl[off];
            }
#pragma unroll
            for (int mi = 0; mi < 2; mi++)
#pragma unroll
                for (int ni = 0; ni < 3; ni++) {
                    f32x4 a = acc[mi][ni];
                    a = __builtin_amdgcn_mfma_f32_16x16x32_bf16(ah[mi], bh[ni], a, 0, 0, 0);
                    a = __builtin_amdgcn_mfma_f32_16x16x32_bf16(ah[mi], bl[ni], a, 0, 0, 0);
                    a = __builtin_amdgcn_mfma_f32_16x16x32_bf16(al2[mi], bh[ni], a, 0, 0, 0);
                    acc[mi][ni] = a;
                }
        }
    }

    // epilogue: atomic accumulate (token slabs race)
    float* kvp = kvout + (size_t)(b * NH_ + h) * FHD_ * HD_;
    float* ksp = ksum + (size_t)(b * NH_ + h) * FHD_;
#pragma unroll
    for (int mi = 0; mi < 2; mi++) {
        int mt = wv * 2 + mi;
#pragma unroll
        for (int r = 0; r < 4; r++) {
            int f = mt * 16 + kq * 4 + r;
            atomicAdd(&kvp[(size_t)f * HD_ + mrow], acc[mi][0][r]);
            atomicAdd(&kvp[(size_t)f * HD_ + 16 + mrow], acc[mi][1][r]);
            if (mrow == 0) atomicAdd(&ksp[f], acc[mi][2][r]);
        }
    }
}

// ---------------------------------------------------------------- attention lookup -> bf16 hi/lo
__global__ __launch_bounds__(256) void attn_kernel(const float* __restrict__ qbuf,
                                                   const float* __restrict__ kvin,
                                                   const float* __restrict__ ksum,
                                                   unsigned short* __restrict__ ohi,
                                                   unsigned short* __restrict__ olo) {
    int chunk = blockIdx.x;
    int h = blockIdx.y, b = blockIdx.z;
    int t = threadIdx.x;
    __shared__ float kvS[128][32];
    __shared__ float qS[128][33];
    __shared__ float tS[128][4];
    __shared__ float ksS[128];
    __shared__ float zS[128];
    int n0 = chunk * 128;

    const float* kvp = kvin + ((size_t)(b * NH_ + h)) * FHD_ * HD_;
#pragma unroll
    for (int r = 0; r < 16; r++) {
        int idx = t + r * 256;
        (&kvS[0][0])[idx] = abs_clamp(kvp[idx]);
    }
    if (t < 128) ksS[t] = ksum[(size_t)(b * NH_ + h) * FHD_ + t];
#pragma unroll
    for (int r = 0; r < 16; r++) {
        int idx = t + r * 256;
        int tok = idx >> 5, d = idx & 31;
        qS[tok][d] = qbuf[((size_t)b * N_ + n0 + tok) * CF_ + h * HD_ + d];
    }
    if (t < 128) {
        int n = n0 + t;
        float ra = (float)(n >> 6), cb = (float)(n & 63);
        float aa = (PI2F * ra) / 64.0f;
        float ab = (PI2F * cb) / 64.0f;
        tS[t][0] = cosf(aa); tS[t][1] = sinf(aa);
        tS[t][2] = cosf(ab); tS[t][3] = sinf(ab);
    }
    __syncthreads();
    if (t < 128) {
        float s = 0.f;
        for (int f = 0; f < 128; f++) s += qS[t][f & 31] * tS[t][f >> 5] * ksS[f];
        zS[t] = abs_clamp(1.f / (s + EPS_));
    }
    __syncthreads();

    int tx = t & 7, ty = t >> 3;
    float acc[4][4];
#pragma unroll
    for (int u = 0; u < 4; u++)
#pragma unroll
        for (int w = 0; w < 4; w++) acc[u][w] = 0.f;

#pragma unroll
    for (int ti = 0; ti < 4; ti++) {
        float tr0 = tS[ty * 4 + 0][ti];
        float tr1 = tS[ty * 4 + 1][ti];
        float tr2 = tS[ty * 4 + 2][ti];
        float tr3 = tS[ty * 4 + 3][ti];
        for (int dd = 0; dd < 32; dd++) {
            int f = ti * 32 + dd;
            float4 kvv = *(const float4*)&kvS[f][tx * 4];
            float q0 = qS[ty * 4 + 0][dd] * tr0;
            float q1 = qS[ty * 4 + 1][dd] * tr1;
            float q2 = qS[ty * 4 + 2][dd] * tr2;
            float q3 = qS[ty * 4 + 3][dd] * tr3;
            acc[0][0] += q0 * kvv.x; acc[0][1] += q0 * kvv.y; acc[0][2] += q0 * kvv.z; acc[0][3] += q0 * kvv.w;
            acc[1][0] += q1 * kvv.x; acc[1][1] += q1 * kvv.y; acc[1][2] += q1 * kvv.z; acc[1][3] += q1 * kvv.w;
            acc[2][0] += q2 * kvv.x; acc[2][1] += q2 * kvv.y; acc[2][2] += q2 * kvv.z; acc[2][3] += q2 * kvv.w;
            acc[3][0] += q3 * kvv.x; acc[3][1] += q3 * kvv.y; acc[3][2] += q3 * kvv.z; acc[3][3] += q3 * kvv.w;
        }
    }

#pragma unroll
    for (int u = 0; u < 4; u++) {
        int tok = ty * 4 + u;
        float z = zS[tok];
        float ov[4];
        ov[0] = abs_clamp(abs_clamp(acc[u][0]) * z);
        ov[1] = abs_clamp(abs_clamp(acc[u][1]) * z);
        ov[2] = abs_clamp(abs_clamp(acc[u][2]) * z);
        ov[3] = abs_clamp(abs_clamp(acc[u][3]) * z);
        u16x4 hv, lv;
#pragma unroll
        for (int w = 0; w < 4; w++) {
            unsigned short hh = f2bf(ov[w]);
            hv[w] = hh;
            lv[w] = f2bf(ov[w] - bf2f(hh));
        }
        size_t base = ((size_t)b * N_ + n0 + tok) * CF_ + h * HD_ + tx * 4;
        *(u16x4*)&ohi[base] = hv;
        *(u16x4*)&olo[base] = lv;
    }
}

// ----------------------------------------------------------------
extern "C" void kernel_launch(void* const* d_in, const int* in_sizes, int n_in,
                              void* d_out, int out_size, void* d_ws, size_t ws_size,
                              hipStream_t stream) {
    (void)in_sizes; (void)n_in; (void)out_size; (void)ws_size;
    const float* query = (const float*)d_in[0];
    const float* Wq = (const float*)d_in[1];
    const float* bq = (const float*)d_in[2];
    const float* Wk = (const float*)d_in[3];
    const float* bk = (const float*)d_in[4];
    const float* Wv = (const float*)d_in[5];
    const float* bv = (const float*)d_in[6];
    const float* Wo = (const float*)d_in[7];
    const float* bo = (const float*)d_in[8];
    const float* Wse1 = (const float*)d_in[9];
    const float* Wse2 = (const float*)d_in[10];
    float* out = (float*)d_out;

    unsigned char* ws = (unsigned char*)d_ws;
    const size_t MB = 1024ull * 1024ull;
    float* qb = (float*)(ws + 0);                      // [65536,256] fp32
    float* kb = (float*)(ws + 64 * MB);                // [65536,256] fp32
    float* vb = (float*)(ws + 128 * MB);               // [65536,256] fp32
    unsigned short* wcat_hi = (unsigned short*)(ws + 192 * MB);
    unsigned short* wcat_lo = (unsigned short*)(ws + 192 * MB + 786432);
    unsigned short* wo_hi   = (unsigned short*)(ws + 192 * MB + 1572864);
    unsigned short* wo_lo   = (unsigned short*)(ws + 192 * MB + 1835008);
    float* kvb = (float*)(ws + 192 * MB + 2097152);
    float* ksb = (float*)(ws + 194 * MB + 2097152);
    float* ssb = (float*)(ws + 194 * MB + 2162688);
    float* sgb = (float*)(ws + 194 * MB + 2195456);
    unsigned short* ohi = (unsigned short*)(ws + 64 * MB);
    unsigned short* olo = (unsigned short*)(ws + 64 * MB + 32 * MB);

    hipMemsetAsync(kvb, 0, 2097152 + 65536 + 32768, stream);

    convert_w<<<2048, 256, 0, stream>>>(Wq, Wk, Wv, Wo, wcat_hi, wcat_lo, wo_hi, wo_lo);
    se_sum_kernel<<<dim3(B_, 16), 256, 0, stream>>>(query, ssb);
    se_gate_kernel<<<B_, 256, 0, stream>>>(ssb, Wse1, Wse2, sgb);
    gemm_mfma<0><<<dim3(6, 512), 256, 0, stream>>>(query, nullptr, nullptr, wcat_hi, wcat_lo,
                                                   bq, bk, bv, nullptr, qb, kb, vb);
    kv_mfma_kernel<<<dim3(8, NH_, B_), 256, 0, stream>>>(kb, vb, kvb, ksb);
    attn_kernel<<<dim3(32, NH_, B_), 256, 0, stream>>>(qb, kvb, ksb, ohi, olo);
    gemm_mfma<1><<<dim3(4, 512), 256, 0, stream>>>(nullptr, ohi, olo, wo_hi, wo_lo,
                                                   bo, nullptr, nullptr, sgb, out, nullptr, nullptr);
}

// Round 4
// 598.605 us; speedup vs baseline: 2.4113x; 1.1723x over previous
//
#include <hip/hip_runtime.h>
#include <math.h>

#define B_   16
#define N_   4096
#define C_   512
#define CF_  256
#define NH_  8
#define HD_  32
#define FHD_ 128
#define EPS_ 1e-4f
#define PI2F 1.5707963267948966f

typedef _Float16 half8 __attribute__((ext_vector_type(8)));
typedef _Float16 half4 __attribute__((ext_vector_type(4)));
typedef float f32x4 __attribute__((ext_vector_type(4)));
typedef unsigned short u16x8 __attribute__((ext_vector_type(8)));

__device__ __forceinline__ float abs_clamp(float t) {
    float a = fminf(fmaxf(fabsf(t), 1e-4f), 1e4f);
    return t > 0.f ? a : (t < 0.f ? -a : 0.f);
}
__device__ __forceinline__ void gld16(const void* g, void* l) {
    __builtin_amdgcn_global_load_lds(
        (const __attribute__((address_space(1))) void*)g,
        (__attribute__((address_space(3))) void*)l, 16, 0, 0);
}

// ---------------------------------------------------------------- SE: mean over tokens
__global__ __launch_bounds__(256) void se_sum_kernel(const float* __restrict__ q,
                                                     float* __restrict__ sesum) {
    int b = blockIdx.x, chunk = blockIdx.y;
    int c = threadIdx.x;
    const float* p = q + ((size_t)b * N_ + (size_t)chunk * 256) * C_;
    float a0 = 0.f, a1 = 0.f;
    for (int n = 0; n < 256; n++) {
        a0 += p[(size_t)n * C_ + c];
        a1 += p[(size_t)n * C_ + c + 256];
    }
    atomicAdd(&sesum[b * C_ + c], a0);
    atomicAdd(&sesum[b * C_ + c + 256], a1);
}

// ---------------------------------------------------------------- SE: 2-layer MLP + sigmoid
__global__ __launch_bounds__(256) void se_gate_kernel(const float* __restrict__ sesum,
                                                      const float* __restrict__ Wse1,
                                                      const float* __restrict__ Wse2,
                                                      float* __restrict__ segate) {
    __shared__ float sm[C_];
    __shared__ float hm[C_ / 2];
    int b = blockIdx.x, t = threadIdx.x;
    sm[t]       = sesum[b * C_ + t]       * (1.f / N_);
    sm[t + 256] = sesum[b * C_ + t + 256] * (1.f / N_);
    __syncthreads();
    {
        const float* w = Wse1 + (size_t)t * C_;
        float acc = 0.f;
        for (int c2 = 0; c2 < C_; c2++) acc += sm[c2] * w[c2];
        hm[t] = fmaxf(acc, 0.f);
    }
    __syncthreads();
    for (int r = 0; r < 2; r++) {
        int c2 = t + r * 256;
        const float* w2 = Wse2 + (size_t)c2 * (C_ / 2);
        float a2 = 0.f;
        for (int j = 0; j < C_ / 2; j++) a2 += hm[j] * w2[j];
        segate[b * C_ + c2] = 1.f / (1.f + expf(-a2));
    }
}

// ---------------------------------------------------------------- weight convert to f16
__global__ __launch_bounds__(256) void convert_w(const float* __restrict__ Wq,
                                                 const float* __restrict__ Wk,
                                                 const float* __restrict__ Wv,
                                                 const float* __restrict__ Wo,
                                                 _Float16* __restrict__ wcat,
                                                 _Float16* __restrict__ wo16) {
    int i = blockIdx.x * 256 + threadIdx.x;
    if (i < 768 * 512) {
        int r = i >> 9, c = i & 511;
        float w = (r < 256) ? Wq[(size_t)r * 512 + c]
                : (r < 512) ? Wk[(size_t)(r - 256) * 512 + c]
                            : Wv[(size_t)(r - 512) * 512 + c];
        wcat[i] = (_Float16)w;
    } else {
        int j = i - 768 * 512;
        wo16[j] = (_Float16)Wo[j];
    }
}

// ---------------------------------------------------------------- f16 MFMA GEMM
// C[m,n] = A[m,:] . B[n,:]
// MODE 0: A = query fp32 (convert to f16 in staging), B = wcat f16 [768,512],
//         out q/k/v f16 (+bias, relu for q/k)
// MODE 1: A = out_attn f16 [M,256] via global_load_lds, B = wo f16 [512,256],
//         out fp32 (+bo, clamp, SE gate)
template <int MODE>
__global__ __launch_bounds__(256) void gemm_mfma(
    const float* __restrict__ Afp,
    const _Float16* __restrict__ A16,
    const _Float16* __restrict__ Bw,
    const float* __restrict__ bias0, const float* __restrict__ bias1,
    const float* __restrict__ bias2, const float* __restrict__ sg,
    _Float16* __restrict__ O0, _Float16* __restrict__ O1, _Float16* __restrict__ O2,
    float* __restrict__ Of) {
    constexpr int K = (MODE == 0) ? 512 : 256;
    constexpr int NITER = K / 32;

    __shared__ __align__(16) unsigned short As[128 * 32];
    __shared__ __align__(16) unsigned short Bs[128 * 32];

    const int t = threadIdx.x;
    const int bx = blockIdx.x;
    const int Mb = blockIdx.y * 128;
    const int nrow0 = bx * 128;

    const int lane = t & 63;
    const int wv = t >> 6;
    const int mq = (wv >> 1) * 64;
    const int nq = (wv & 1) * 64;
    const int mrow = lane & 15;
    const int kq = lane >> 4;
    const int fragoff = mrow * 32 + ((kq ^ ((mrow >> 1) & 3)) * 8);

    // B staging: 512 16B-chunks per iter, 2 per thread, XOR chunk swizzle
    const unsigned char* bsrc[2];
    unsigned short* bdst[2];
    {
        int cid0 = t, cid1 = t + 256;
        int m0 = cid0 >> 2, c0 = (cid0 & 3) ^ ((m0 >> 1) & 3);
        int m1 = cid1 >> 2, c1 = (cid1 & 3) ^ ((m1 >> 1) & 3);
        bsrc[0] = (const unsigned char*)(Bw + (size_t)(nrow0 + m0) * K + c0 * 8);
        bsrc[1] = (const unsigned char*)(Bw + (size_t)(nrow0 + m1) * K + c1 * 8);
        bdst[0] = &Bs[cid0 * 8];
        bdst[1] = &Bs[cid1 * 8];
    }
    // A staging
    const unsigned char* asrc[2];
    unsigned short* adst[2];
    const float* afp_src = nullptr;
    unsigned short *adst_h0 = nullptr, *adst_h1 = nullptr;
    if (MODE == 1) {
        int cid0 = t, cid1 = t + 256;
        int m0 = cid0 >> 2, c0 = (cid0 & 3) ^ ((m0 >> 1) & 3);
        int m1 = cid1 >> 2, c1 = (cid1 & 3) ^ ((m1 >> 1) & 3);
        asrc[0] = (const unsigned char*)(A16 + (size_t)(Mb + m0) * K + c0 * 8);
        asrc[1] = (const unsigned char*)(A16 + (size_t)(Mb + m1) * K + c1 * 8);
        adst[0] = &As[cid0 * 8];
        adst[1] = &As[cid1 * 8];
    } else {
        int m0 = t >> 1, h2 = t & 1, sm = (m0 >> 1) & 3;
        afp_src = Afp + (size_t)(Mb + m0) * C_ + h2 * 16;
        adst_h0 = &As[m0 * 32 + (((2 * h2) ^ sm) * 8)];
        adst_h1 = &As[m0 * 32 + (((2 * h2 + 1) ^ sm) * 8)];
    }

    f32x4 acc[4][4];
#pragma unroll
    for (int mi = 0; mi < 4; mi++)
#pragma unroll
        for (int ni = 0; ni < 4; ni++) acc[mi][ni] = (f32x4){0.f, 0.f, 0.f, 0.f};

#pragma unroll 1
    for (int it = 0; it < NITER; ++it) {
        __syncthreads();
        if (MODE == 0) {
            const float* s = afp_src + it * 32;
            float va[16] __attribute__((aligned(16)));
            *(float4*)(va + 0)  = *(const float4*)(s + 0);
            *(float4*)(va + 4)  = *(const float4*)(s + 4);
            *(float4*)(va + 8)  = *(const float4*)(s + 8);
            *(float4*)(va + 12) = *(const float4*)(s + 12);
            half8 h0, h1;
#pragma unroll
            for (int ii = 0; ii < 8; ii++) h0[ii] = (_Float16)va[ii];
#pragma unroll
            for (int ii = 0; ii < 8; ii++) h1[ii] = (_Float16)va[8 + ii];
            *(half8*)adst_h0 = h0;
            *(half8*)adst_h1 = h1;
        } else {
            gld16(asrc[0] + it * 64, adst[0]);
            gld16(asrc[1] + it * 64, adst[1]);
        }
        gld16(bsrc[0] + it * 64, bdst[0]);
        gld16(bsrc[1] + it * 64, bdst[1]);
        __syncthreads();

        half8 ah[4], bh[4];
#pragma unroll
        for (int mi = 0; mi < 4; mi++)
            ah[mi] = *(const half8*)&As[(mq + mi * 16) * 32 + fragoff];
#pragma unroll
        for (int ni = 0; ni < 4; ni++)
            bh[ni] = *(const half8*)&Bs[(nq + ni * 16) * 32 + fragoff];
#pragma unroll
        for (int mi = 0; mi < 4; mi++)
#pragma unroll
            for (int ni = 0; ni < 4; ni++)
                acc[mi][ni] = __builtin_amdgcn_mfma_f32_16x16x32_f16(ah[mi], bh[ni], acc[mi][ni], 0, 0, 0);
    }

    if (MODE == 0) {
        int mat = bx >> 1;
        int nc0 = (bx & 1) * 128;
        const float* bias = (mat == 0) ? bias0 : (mat == 1) ? bias1 : bias2;
        _Float16* O = (mat == 0) ? O0 : (mat == 1) ? O1 : O2;
#pragma unroll
        for (int ni = 0; ni < 4; ni++) {
            int cg = nc0 + nq + ni * 16 + mrow;
            float bb = bias[cg];
#pragma unroll
            for (int mi = 0; mi < 4; mi++)
#pragma unroll
                for (int r = 0; r < 4; r++) {
                    int m = Mb + mq + mi * 16 + kq * 4 + r;
                    float v2 = acc[mi][ni][r] + bb;
                    if (mat < 2) v2 = fmaxf(v2, 0.f);
                    O[(size_t)m * CF_ + cg] = (_Float16)v2;
                }
        }
    } else {
        int b = Mb >> 12;
#pragma unroll
        for (int ni = 0; ni < 4; ni++) {
            int cg = nrow0 + nq + ni * 16 + mrow;
            float bb = bias0[cg];
            float gv = sg[b * C_ + cg];
#pragma unroll
            for (int mi = 0; mi < 4; mi++)
#pragma unroll
                for (int r = 0; r < 4; r++) {
                    int m = Mb + mq + mi * 16 + kq * 4 + r;
                    float v2 = abs_clamp(acc[mi][ni][r] + bb);
                    v2 = abs_clamp(v2 * (1.f + gv));
                    Of[(size_t)m * C_ + cg] = v2;
                }
        }
    }
}

// ---------------------------------------------------------------- kv state + k_sum via f16 MFMA
// Per (b,h): C[f=128][d=32] = sum_n trig(f>>5,n)*k[n,f&31] * v[n,d]; ksum via ones-row 32.
__global__ __launch_bounds__(256) void kv_mfma_kernel(const _Float16* __restrict__ kin,
                                                      const _Float16* __restrict__ vin,
                                                      float* __restrict__ kvout,
                                                      float* __restrict__ ksum) {
    __shared__ __align__(16) unsigned short Ah[128 * 64];
    __shared__ __align__(16) unsigned short Bh[48 * 64];

    const int t = threadIdx.x;
    const int c8 = blockIdx.x;           // 512-token slab
    const int h = blockIdx.y, b = blockIdx.z;
    const int dp = t & 31;               // channel within head
    const int octet = t >> 5;            // token octet

    // constant B rows 32..47: row 32 = ones(f16), rest zero (written once)
    if (t < 128) {
        int r = 32 + (t & 15);
        int oc = t >> 4;                 // 0..7
        int off = r * 64 + (((oc ^ ((r >> 3) & 7)) & 7) * 8);
        unsigned short fill = (r == 32) ? (unsigned short)0x3C00 : (unsigned short)0;
        u16x8 z = {fill, fill, fill, fill, fill, fill, fill, fill};
        *(u16x8*)&Bh[off] = z;
    }

    float cbv[8], sbv[8];
#pragma unroll
    for (int i = 0; i < 8; i++) {
        float ang = (PI2F / 64.f) * (float)(octet * 8 + i);
        cbv[i] = cosf(ang);
        sbv[i] = sinf(ang);
    }

    const int lane = t & 63;
    const int wv = t >> 6;
    const int mrow = lane & 15;
    const int kq = lane >> 4;

    f32x4 acc[2][3];
#pragma unroll
    for (int mi = 0; mi < 2; mi++)
#pragma unroll
        for (int ni = 0; ni < 3; ni++) acc[mi][ni] = (f32x4){0.f, 0.f, 0.f, 0.f};

    int offA[4];
#pragma unroll
    for (int tvar = 0; tvar < 4; tvar++) {
        int f = tvar * 32 + dp;
        offA[tvar] = f * 64 + (((octet ^ ((f >> 3) & 7)) & 7) * 8);
    }
    const int offB = dp * 64 + (((octet ^ ((dp >> 3) & 7)) & 7) * 8);

#pragma unroll 1
    for (int ch = 0; ch < 8; ch++) {
        const int n0 = c8 * 512 + ch * 64;
        const int rrow = n0 >> 6;
        float aang = (PI2F / 64.f) * (float)rrow;
        float ca = cosf(aang), sa = sinf(aang);

        const _Float16* kp = kin + ((size_t)b * N_ + n0 + octet * 8) * CF_ + h * HD_ + dp;
        const _Float16* vp = vin + ((size_t)b * N_ + n0 + octet * 8) * CF_ + h * HD_ + dp;
        float kvl[8];
        _Float16 vvl[8];
#pragma unroll
        for (int i = 0; i < 8; i++) kvl[i] = (float)kp[(size_t)i * CF_];
#pragma unroll
        for (int i = 0; i < 8; i++) vvl[i] = vp[(size_t)i * CF_];

        __syncthreads();   // previous chunk's fragment reads done

#pragma unroll
        for (int tvar = 0; tvar < 4; tvar++) {
            half8 hv;
#pragma unroll
            for (int i = 0; i < 8; i++) {
                float val = kvl[i] * (tvar == 0 ? ca : tvar == 1 ? sa : tvar == 2 ? cbv[i] : sbv[i]);
                hv[i] = (_Float16)val;
            }
            *(half8*)&Ah[offA[tvar]] = hv;
        }
        {
            half8 hv;
#pragma unroll
            for (int i = 0; i < 8; i++) hv[i] = vvl[i];
            *(half8*)&Bh[offB] = hv;
        }
        __syncthreads();

#pragma unroll
        for (int s = 0; s < 2; s++) {
            half8 ah[2], bh[3];
            int koct = s * 4 + kq;
#pragma unroll
            for (int mi = 0; mi < 2; mi++) {
                int f = (wv * 2 + mi) * 16 + mrow;
                ah[mi] = *(const half8*)&Ah[f * 64 + (((koct ^ ((f >> 3) & 7)) & 7) * 8)];
            }
#pragma unroll
            for (int ni = 0; ni < 3; ni++) {
                int nr = ni * 16 + mrow;
                bh[ni] = *(const half8*)&Bh[nr * 64 + (((koct ^ ((nr >> 3) & 7)) & 7) * 8)];
            }
#pragma unroll
            for (int mi = 0; mi < 2; mi++)
#pragma unroll
                for (int ni = 0; ni < 3; ni++)
                    acc[mi][ni] = __builtin_amdgcn_mfma_f32_16x16x32_f16(ah[mi], bh[ni], acc[mi][ni], 0, 0, 0);
        }
    }

    float* kvp = kvout + (size_t)(b * NH_ + h) * FHD_ * HD_;
    float* ksp = ksum + (size_t)(b * NH_ + h) * FHD_;
#pragma unroll
    for (int mi = 0; mi < 2; mi++) {
        int mt = wv * 2 + mi;
#pragma unroll
        for (int r = 0; r < 4; r++) {
            int f = mt * 16 + kq * 4 + r;
            atomicAdd(&kvp[(size_t)f * HD_ + mrow], acc[mi][0][r]);
            atomicAdd(&kvp[(size_t)f * HD_ + 16 + mrow], acc[mi][1][r]);
            if (mrow == 0) atomicAdd(&ksp[f], acc[mi][2][r]);
        }
    }
}

// ---------------------------------------------------------------- attention lookup -> f16
__global__ __launch_bounds__(256) void attn_kernel(const _Float16* __restrict__ qbuf,
                                                   const float* __restrict__ kvin,
                                                   const float* __restrict__ ksum,
                                                   _Float16* __restrict__ ob) {
    int chunk = blockIdx.x;
    int h = blockIdx.y, b = blockIdx.z;
    int t = threadIdx.x;
    __shared__ float kvS[128][32];
    __shared__ float qS[128][33];
    __shared__ float tS[128][4];
    __shared__ float ksS[128];
    __shared__ float zS[128];
    int n0 = chunk * 128;

    const float* kvp = kvin + ((size_t)(b * NH_ + h)) * FHD_ * HD_;
#pragma unroll
    for (int r = 0; r < 16; r++) {
        int idx = t + r * 256;
        (&kvS[0][0])[idx] = abs_clamp(kvp[idx]);
    }
    if (t < 128) ksS[t] = ksum[(size_t)(b * NH_ + h) * FHD_ + t];
#pragma unroll
    for (int r = 0; r < 16; r++) {
        int idx = t + r * 256;
        int tok = idx >> 5, d = idx & 31;
        qS[tok][d] = (float)qbuf[((size_t)b * N_ + n0 + tok) * CF_ + h * HD_ + d];
    }
    if (t < 128) {
        int n = n0 + t;
        float ra = (float)(n >> 6), cb = (float)(n & 63);
        float aa = (PI2F * ra) / 64.0f;
        float ab = (PI2F * cb) / 64.0f;
        tS[t][0] = cosf(aa); tS[t][1] = sinf(aa);
        tS[t][2] = cosf(ab); tS[t][3] = sinf(ab);
    }
    __syncthreads();
    if (t < 128) {
        float s = 0.f;
        for (int f = 0; f < 128; f++) s += qS[t][f & 31] * tS[t][f >> 5] * ksS[f];
        zS[t] = abs_clamp(1.f / (s + EPS_));
    }
    __syncthreads();

    int tx = t & 7, ty = t >> 3;
    float acc[4][4];
#pragma unroll
    for (int u = 0; u < 4; u++)
#pragma unroll
        for (int w = 0; w < 4; w++) acc[u][w] = 0.f;

#pragma unroll
    for (int ti = 0; ti < 4; ti++) {
        float tr0 = tS[ty * 4 + 0][ti];
        float tr1 = tS[ty * 4 + 1][ti];
        float tr2 = tS[ty * 4 + 2][ti];
        float tr3 = tS[ty * 4 + 3][ti];
        for (int dd = 0; dd < 32; dd++) {
            int f = ti * 32 + dd;
            float4 kvv = *(const float4*)&kvS[f][tx * 4];
            float q0 = qS[ty * 4 + 0][dd] * tr0;
            float q1 = qS[ty * 4 + 1][dd] * tr1;
            float q2 = qS[ty * 4 + 2][dd] * tr2;
            float q3 = qS[ty * 4 + 3][dd] * tr3;
            acc[0][0] += q0 * kvv.x; acc[0][1] += q0 * kvv.y; acc[0][2] += q0 * kvv.z; acc[0][3] += q0 * kvv.w;
            acc[1][0] += q1 * kvv.x; acc[1][1] += q1 * kvv.y; acc[1][2] += q1 * kvv.z; acc[1][3] += q1 * kvv.w;
            acc[2][0] += q2 * kvv.x; acc[2][1] += q2 * kvv.y; acc[2][2] += q2 * kvv.z; acc[2][3] += q2 * kvv.w;
            acc[3][0] += q3 * kvv.x; acc[3][1] += q3 * kvv.y; acc[3][2] += q3 * kvv.z; acc[3][3] += q3 * kvv.w;
        }
    }

#pragma unroll
    for (int u = 0; u < 4; u++) {
        int tok = ty * 4 + u;
        float z = zS[tok];
        half4 hv;
        hv[0] = (_Float16)abs_clamp(abs_clamp(acc[u][0]) * z);
        hv[1] = (_Float16)abs_clamp(abs_clamp(acc[u][1]) * z);
        hv[2] = (_Float16)abs_clamp(abs_clamp(acc[u][2]) * z);
        hv[3] = (_Float16)abs_clamp(abs_clamp(acc[u][3]) * z);
        size_t base = ((size_t)b * N_ + n0 + tok) * CF_ + h * HD_ + tx * 4;
        *(half4*)&ob[base] = hv;
    }
}

// ----------------------------------------------------------------
extern "C" void kernel_launch(void* const* d_in, const int* in_sizes, int n_in,
                              void* d_out, int out_size, void* d_ws, size_t ws_size,
                              hipStream_t stream) {
    (void)in_sizes; (void)n_in; (void)out_size; (void)ws_size;
    const float* query = (const float*)d_in[0];
    const float* Wq = (const float*)d_in[1];
    const float* bq = (const float*)d_in[2];
    const float* Wk = (const float*)d_in[3];
    const float* bk = (const float*)d_in[4];
    const float* Wv = (const float*)d_in[5];
    const float* bv = (const float*)d_in[6];
    const float* Wo = (const float*)d_in[7];
    const float* bo = (const float*)d_in[8];
    const float* Wse1 = (const float*)d_in[9];
    const float* Wse2 = (const float*)d_in[10];
    float* out = (float*)d_out;

    unsigned char* ws = (unsigned char*)d_ws;
    const size_t MB = 1024ull * 1024ull;
    _Float16* qb = (_Float16*)(ws + 0);        // [65536,256] f16, 32 MiB
    _Float16* kb = (_Float16*)(ws + 32 * MB);  // [65536,256] f16
    _Float16* vb = (_Float16*)(ws + 64 * MB);  // [65536,256] f16
    _Float16* ob = (_Float16*)(ws + 96 * MB);  // [65536,256] f16 out_attn
    _Float16* wcat = (_Float16*)(ws + 128 * MB);            // [768,512] f16, 786432 B
    _Float16* wo16 = (_Float16*)(ws + 128 * MB + 786432);   // [512,256] f16, 262144 B
    float* kvb = (float*)(ws + 129 * MB);                   // [16,8,128,32] 2 MiB
    float* ksb = (float*)(ws + 131 * MB);                   // [16,8,128]
    float* ssb = (float*)(ws + 131 * MB + 65536);           // [16,512]
    float* sgb = (float*)(ws + 131 * MB + 98304);           // [16,512]

    // zero atomic accumulators (kvb, ksb, ssb contiguous)
    hipMemsetAsync(kvb, 0, 2097152 + 65536 + 32768, stream);

    convert_w<<<2048, 256, 0, stream>>>(Wq, Wk, Wv, Wo, wcat, wo16);
    se_sum_kernel<<<dim3(B_, 16), 256, 0, stream>>>(query, ssb);
    se_gate_kernel<<<B_, 256, 0, stream>>>(ssb, Wse1, Wse2, sgb);
    gemm_mfma<0><<<dim3(6, 512), 256, 0, stream>>>(query, nullptr, wcat,
                                                   bq, bk, bv, nullptr,
                                                   qb, kb, vb, nullptr);
    kv_mfma_kernel<<<dim3(8, NH_, B_), 256, 0, stream>>>(kb, vb, kvb, ksb);
    attn_kernel<<<dim3(32, NH_, B_), 256, 0, stream>>>(qb, kvb, ksb, ob);
    gemm_mfma<1><<<dim3(4, 512), 256, 0, stream>>>(nullptr, ob, wo16,
                                                   bo, nullptr, nullptr, sgb,
                                                   nullptr, nullptr, nullptr, out);
}